// Round 1
// baseline (1184.975 us; speedup 1.0000x reference)
//
#include <hip/hip_runtime.h>
#include <hip/hip_bf16.h>

// Problem constants
#define SB 2048
#define DB 512
#define HB 8
#define DKB 64
#define DFB 2048
#define BATCH 4

typedef __attribute__((ext_vector_type(8))) short bf16x8;
typedef __attribute__((ext_vector_type(4))) float f32x4;

static __device__ __forceinline__ short f2bf(float x) {
  union { float f; unsigned u; } v; v.f = x;
  unsigned r = (v.u + 0x7fffu + ((v.u >> 16) & 1u)) >> 16;
  return (short)(unsigned short)r;
}

static __device__ __forceinline__ f32x4 mfma16(bf16x8 a, bf16x8 b, f32x4 c) {
  return __builtin_amdgcn_mfma_f32_16x16x32_bf16(a, b, c, 0, 0, 0);
}

// ---------------- weight prep ----------------
__global__ __launch_bounds__(256) void conv_kernel(const float* __restrict__ src,
                                                   short* __restrict__ dst, int n) {
  int i = blockIdx.x * 256 + threadIdx.x;
  if (i < n) dst[i] = f2bf(src[i]);
}

// dst[n*K + k] = src[k*N + n] * scale   (produce B^T, bf16)
__global__ __launch_bounds__(256) void tconv_kernel(const float* __restrict__ src,
                                                    short* __restrict__ dst,
                                                    int K, int N, float scale) {
  int i = blockIdx.x * 256 + threadIdx.x;
  if (i >= K * N) return;
  int n = i / K, k = i - n * K;
  dst[i] = f2bf(src[(size_t)k * N + n] * scale);
}

// ---------------- layernorm (row per block, D=512) ----------------
__global__ __launch_bounds__(256) void ln_kernel(const float* __restrict__ in,
                                                 const float* __restrict__ g,
                                                 const float* __restrict__ bb,
                                                 short* __restrict__ out) {
  int row = blockIdx.x;
  const float* xr = in + (size_t)row * DB;
  int t = threadIdx.x;
  float x0 = xr[t], x1 = xr[t + 256];
  float s = x0 + x1, s2 = x0 * x0 + x1 * x1;
#pragma unroll
  for (int off = 1; off < 64; off <<= 1) {
    s += __shfl_xor(s, off, 64);
    s2 += __shfl_xor(s2, off, 64);
  }
  __shared__ float r1[4], r2[4];
  int w = t >> 6;
  if ((t & 63) == 0) { r1[w] = s; r2[w] = s2; }
  __syncthreads();
  s = r1[0] + r1[1] + r1[2] + r1[3];
  s2 = r2[0] + r2[1] + r2[2] + r2[3];
  float mean = s * (1.f / DB);
  float var = s2 * (1.f / DB) - mean * mean;
  float rstd = rsqrtf(var + 1e-6f);
  short* orow = out + (size_t)row * DB;
  orow[t] = f2bf((x0 - mean) * rstd * g[t] + bb[t]);
  orow[t + 256] = f2bf((x1 - mean) * rstd * g[t + 256] + bb[t + 256]);
}

// ---------------- GEMM: C[M,N] = A[M,K]bf16 * BT[N,K]bf16 ----------------
// 4 waves, 64x64 tile, direct global loads. Epilogues:
//  EPI 0: QKV split -> Q,K,[VT] bf16    EPI 1: float out = resid + acc + bias
//  EPI 2: bf16 out = relu(acc + bias)
template <int KD, int EPI>
__global__ __launch_bounds__(256) void gemm_kernel(
    const short* __restrict__ A, const short* __restrict__ BT,
    const float* __restrict__ bias, const float* __restrict__ resid,
    short* __restrict__ o0, short* __restrict__ o1, short* __restrict__ o2,
    float* __restrict__ of) {
  int tid = threadIdx.x;
  int l = tid & 63, w = tid >> 6;
  int wr = w >> 1, wc = w & 1;
  int lr = l & 15, lq = l >> 4;
  size_t row0 = (size_t)blockIdx.y * 64 + wr * 32;
  size_t col0 = (size_t)blockIdx.x * 64 + wc * 32;

  f32x4 acc[2][2];
#pragma unroll
  for (int a = 0; a < 2; ++a)
#pragma unroll
    for (int b = 0; b < 2; ++b) acc[a][b] = (f32x4){0.f, 0.f, 0.f, 0.f};

  const short* ap = A + (row0 + lr) * KD + lq * 8;
  const short* bp = BT + (col0 + lr) * KD + lq * 8;
#pragma unroll 2
  for (int k0 = 0; k0 < KD; k0 += 32) {
    bf16x8 a0 = *(const bf16x8*)(ap + k0);
    bf16x8 a1 = *(const bf16x8*)(ap + (size_t)16 * KD + k0);
    bf16x8 b0 = *(const bf16x8*)(bp + k0);
    bf16x8 b1 = *(const bf16x8*)(bp + (size_t)16 * KD + k0);
    acc[0][0] = mfma16(a0, b0, acc[0][0]);
    acc[0][1] = mfma16(a0, b1, acc[0][1]);
    acc[1][0] = mfma16(a1, b0, acc[1][0]);
    acc[1][1] = mfma16(a1, b1, acc[1][1]);
  }

#pragma unroll
  for (int a = 0; a < 2; ++a)
#pragma unroll
    for (int b = 0; b < 2; ++b)
#pragma unroll
      for (int r = 0; r < 4; ++r) {
        size_t row = row0 + a * 16 + lq * 4 + r;
        size_t col = col0 + b * 16 + lr;
        float val = acc[a][b][r];
        if (EPI == 0) {
          int sect = (int)(col >> 9);
          int hh = (int)((col >> 6) & 7);
          int d = (int)(col & 63);
          size_t b_ = row >> 11, s_ = row & 2047;
          size_t bh = b_ * HB + hh;
          short bv = f2bf(val);
          if (sect == 0) o0[(bh * SB + s_) * DKB + d] = bv;
          else if (sect == 1) o1[(bh * SB + s_) * DKB + d] = bv;
          else o2[(bh * DKB + d) * SB + s_] = bv;  // V transposed
        } else if (EPI == 1) {
          of[row * DB + col] = resid[row * DB + col] + val + bias[col];
        } else {
          float tv = val + bias[col];
          o0[row * DFB + col] = f2bf(tv > 0.f ? tv : 0.f);
        }
      }
}

// ---------------- fused causal attention with relative positions ----------
// 1 wave handles 16 query rows of one (b,h). scores = q.k' + q.E[S-1-i+j].
__global__ __launch_bounds__(256) void attn_kernel(
    const short* __restrict__ Q, const short* __restrict__ Kb,
    const short* __restrict__ VT, const short* __restrict__ Eb,
    short* __restrict__ out) {
  __shared__ short P_lds[4][16][40];
  int l = threadIdx.x & 63, w = threadIdx.x >> 6;
  int lr = l & 15, lq = l >> 4;
  int tile = blockIdx.x * 4 + w;               // B*H*(S/16) = 8192 tiles
  int bh = tile >> 7;                          // tile / (S/16)
  int i0 = (tile & 127) << 4;
  const short* Qh = Q + (size_t)bh * SB * DKB;
  const short* Kh = Kb + (size_t)bh * SB * DKB;
  const short* Vh = VT + (size_t)bh * DKB * SB;
  const short* Eh = Eb + (size_t)(bh & 7) * SB * DKB;

  bf16x8 qf0 = *(const bf16x8*)(Qh + (size_t)(i0 + lr) * DKB + lq * 8);
  bf16x8 qf1 = *(const bf16x8*)(Qh + (size_t)(i0 + lr) * DKB + 32 + lq * 8);

  f32x4 acco[4];
#pragma unroll
  for (int dt = 0; dt < 4; ++dt) acco[dt] = (f32x4){0.f, 0.f, 0.f, 0.f};
  float mrun[4] = {-1e30f, -1e30f, -1e30f, -1e30f};
  float lrun[4] = {0.f, 0.f, 0.f, 0.f};

  int imax = i0 + 15;
  for (int j0 = 0; j0 <= imax; j0 += 32) {
    // ---- QK^T (K already scaled by 1/sqrt(DK)) ----
    f32x4 sc[2];
#pragma unroll
    for (int hh = 0; hh < 2; ++hh) {
      int krow = j0 + hh * 16 + lr;
      if (krow > SB - 1) krow = SB - 1;
      const short* kp = Kh + (size_t)krow * DKB + lq * 8;
      sc[hh] = (f32x4){0.f, 0.f, 0.f, 0.f};
      sc[hh] = mfma16(qf0, *(const bf16x8*)kp, sc[hh]);
      sc[hh] = mfma16(qf1, *(const bf16x8*)(kp + 32), sc[hh]);
    }
    // ---- rel band: R[m][t] = q_m . E[rbase+t], t in [0,48) ----
    int rbase = SB - 16 - i0 + j0;
    f32x4 rr[3];
#pragma unroll
    for (int nt = 0; nt < 3; ++nt) {
      int er = rbase + nt * 16 + lr;
      er = er < 0 ? 0 : (er > SB - 1 ? SB - 1 : er);
      const short* ep = Eh + (size_t)er * DKB + lq * 8;
      rr[nt] = (f32x4){0.f, 0.f, 0.f, 0.f};
      rr[nt] = mfma16(qf0, *(const bf16x8*)ep, rr[nt]);
      rr[nt] = mfma16(qf1, *(const bf16x8*)(ep + 32), rr[nt]);
    }
    // ---- gather rel (t = n-m+15, same 16-lane group), mask, online softmax
#pragma unroll
    for (int r = 0; r < 4; ++r) {
      int m = lq * 4 + r;
      float sv0, sv1;
      {
        int t = lr - m + 15;                       // hh = 0
        int src = (l & 48) | (t & 15);
        float g0 = __shfl(rr[0][r], src, 64);
        float g1 = __shfl(rr[1][r], src, 64);
        float g2 = __shfl(rr[2][r], src, 64);
        float rel = t < 16 ? g0 : (t < 32 ? g1 : g2);
        sv0 = sc[0][r] + rel;
        if (j0 + lr > i0 + m) sv0 = -1e30f;
      }
      {
        int t = 16 + lr - m + 15;                  // hh = 1
        int src = (l & 48) | (t & 15);
        float g0 = __shfl(rr[0][r], src, 64);
        float g1 = __shfl(rr[1][r], src, 64);
        float g2 = __shfl(rr[2][r], src, 64);
        float rel = t < 16 ? g0 : (t < 32 ? g1 : g2);
        sv1 = sc[1][r] + rel;
        if (j0 + 16 + lr > i0 + m) sv1 = -1e30f;
      }
      float tm = fmaxf(sv0, sv1);
#pragma unroll
      for (int off = 1; off < 16; off <<= 1) tm = fmaxf(tm, __shfl_xor(tm, off, 64));
      float mnew = fmaxf(mrun[r], tm);
      float corr = __expf(mrun[r] - mnew);
      float p0 = __expf(sv0 - mnew);
      float p1 = __expf(sv1 - mnew);
      float rs = p0 + p1;
#pragma unroll
      for (int off = 1; off < 16; off <<= 1) rs += __shfl_xor(rs, off, 64);
      lrun[r] = lrun[r] * corr + rs;
      mrun[r] = mnew;
#pragma unroll
      for (int dt = 0; dt < 4; ++dt) acco[dt][r] *= corr;
      P_lds[w][m][lr] = f2bf(p0);
      P_lds[w][m][16 + lr] = f2bf(p1);
    }
    asm volatile("s_waitcnt lgkmcnt(0)" ::: "memory");
    // ---- PV: O += P * V  (V^T rows give B fragments directly) ----
    bf16x8 pa = *(const bf16x8*)(&P_lds[w][lr][lq * 8]);
#pragma unroll
    for (int dt = 0; dt < 4; ++dt) {
      const short* vp = Vh + (size_t)(dt * 16 + lr) * SB + j0 + lq * 8;
      acco[dt] = mfma16(pa, *(const bf16x8*)vp, acco[dt]);
    }
  }
  // ---- epilogue: attn[b, i, h*64+d] = O/l ----
  int b_ = bh >> 3, hd = bh & 7;
#pragma unroll
  for (int r = 0; r < 4; ++r) {
    float inv = 1.f / lrun[r];
    size_t i = i0 + lq * 4 + r;
#pragma unroll
    for (int dt = 0; dt < 4; ++dt) {
      out[((size_t)b_ * SB + i) * DB + hd * DKB + dt * 16 + lr] =
          f2bf(acco[dt][r] * inv);
    }
  }
}

// ---------------- host ----------------
extern "C" void kernel_launch(void* const* d_in, const int* in_sizes, int n_in,
                              void* d_out, int out_size, void* d_ws, size_t ws_size,
                              hipStream_t stream) {
  const float* x    = (const float*)d_in[0];
  const float* wq   = (const float*)d_in[2];
  const float* wk   = (const float*)d_in[3];
  const float* wv   = (const float*)d_in[4];
  const float* w0   = (const float*)d_in[5];
  const float* b0   = (const float*)d_in[6];
  const float* rel  = (const float*)d_in[7];
  const float* ln1g = (const float*)d_in[8];
  const float* ln1b = (const float*)d_in[9];
  const float* ln2g = (const float*)d_in[10];
  const float* ln2b = (const float*)d_in[11];
  const float* fw1  = (const float*)d_in[12];
  const float* fb1  = (const float*)d_in[13];
  const float* fw2  = (const float*)d_in[14];
  const float* fb2  = (const float*)d_in[15];
  float* outp = (float*)d_out;

  // workspace layout (64 MiB total)
  char* ws = (char*)d_ws;
  size_t off = 0;
  auto alloc = [&](size_t bytes) {
    char* p = ws + off;
    off += (bytes + 255) & ~(size_t)255;
    return p;
  };
  short* wqkvT = (short*)alloc((size_t)1536 * 512 * 2);
  short* w0T   = (short*)alloc((size_t)512 * 512 * 2);
  short* fw1T  = (short*)alloc((size_t)2048 * 512 * 2);
  short* fw2T  = (short*)alloc((size_t)512 * 2048 * 2);
  short* relb  = (short*)alloc((size_t)8 * 2048 * 64 * 2);
  short* hbuf  = (short*)alloc((size_t)8192 * 512 * 2);   // ff1 alias starts here
  short* Qb    = (short*)alloc((size_t)8192 * 512 * 2);
  short* Kbf   = (short*)alloc((size_t)8192 * 512 * 2);
  short* VTb   = (short*)alloc((size_t)8192 * 512 * 2);
  short* attnb = (short*)alloc((size_t)8192 * 512 * 2);   // later reused as h2
  float* x2    = (float*)alloc((size_t)8192 * 512 * 4);
  short* ff1 = hbuf;   // 32 MiB alias over h/Q/K/VT (all dead by FF1 time)
  short* h2  = attnb;  // attn dead after O-proj

  dim3 blk(256);
  // weight prep (bf16, transposed; 1/sqrt(DK) folded into wk)
  conv_kernel<<<(8 * 2048 * 64 + 255) / 256, blk, 0, stream>>>(rel, relb, 8 * 2048 * 64);
  tconv_kernel<<<(512 * 512 + 255) / 256, blk, 0, stream>>>(wq, wqkvT, 512, 512, 1.f);
  tconv_kernel<<<(512 * 512 + 255) / 256, blk, 0, stream>>>(wk, wqkvT + 512 * 512, 512, 512, 0.125f);
  tconv_kernel<<<(512 * 512 + 255) / 256, blk, 0, stream>>>(wv, wqkvT + 1024 * 512, 512, 512, 1.f);
  tconv_kernel<<<(512 * 512 + 255) / 256, blk, 0, stream>>>(w0, w0T, 512, 512, 1.f);
  tconv_kernel<<<(512 * 2048 + 255) / 256, blk, 0, stream>>>(fw1, fw1T, 512, 2048, 1.f);
  tconv_kernel<<<(512 * 2048 + 255) / 256, blk, 0, stream>>>(fw2, fw2T, 2048, 512, 1.f);

  ln_kernel<<<8192, blk, 0, stream>>>(x, ln1g, ln1b, hbuf);
  gemm_kernel<512, 0><<<dim3(24, 128), blk, 0, stream>>>(hbuf, wqkvT, nullptr, nullptr,
                                                         Qb, Kbf, VTb, nullptr);
  attn_kernel<<<2048, blk, 0, stream>>>(Qb, Kbf, VTb, relb, attnb);
  gemm_kernel<512, 1><<<dim3(8, 128), blk, 0, stream>>>(attnb, w0T, b0, x,
                                                        nullptr, nullptr, nullptr, x2);
  ln_kernel<<<8192, blk, 0, stream>>>(x2, ln2g, ln2b, h2);
  gemm_kernel<512, 2><<<dim3(32, 128), blk, 0, stream>>>(h2, fw1T, fb1, nullptr,
                                                         ff1, nullptr, nullptr, nullptr);
  gemm_kernel<2048, 1><<<dim3(8, 128), blk, 0, stream>>>(ff1, fw2T, fb2, x2,
                                                         nullptr, nullptr, nullptr, outp);
}

// Round 2
// 682.312 us; speedup vs baseline: 1.7367x; 1.7367x over previous
//
#include <hip/hip_runtime.h>
#include <hip/hip_bf16.h>

// Problem constants
#define SB 2048
#define DB 512
#define HB 8
#define DKB 64
#define DFB 2048
#define BATCH 4

typedef __attribute__((ext_vector_type(8))) short bf16x8;
typedef __attribute__((ext_vector_type(4))) float f32x4;
typedef __attribute__((ext_vector_type(2))) float f32x2;
typedef __attribute__((ext_vector_type(2))) unsigned u32x2;
typedef __attribute__((ext_vector_type(4))) short s16x4;

static __device__ __forceinline__ short f2bf(float x) {
  union { float f; unsigned u; } v; v.f = x;
  unsigned r = (v.u + 0x7fffu + ((v.u >> 16) & 1u)) >> 16;
  return (short)(unsigned short)r;
}

static __device__ __forceinline__ unsigned pack2bf(float a, float b) {
  return (unsigned)(unsigned short)f2bf(a) | ((unsigned)(unsigned short)f2bf(b) << 16);
}

static __device__ __forceinline__ f32x4 mfma16(bf16x8 a, bf16x8 b, f32x4 c) {
  return __builtin_amdgcn_mfma_f32_16x16x32_bf16(a, b, c, 0, 0, 0);
}

// ---------------- weight prep ----------------
__global__ __launch_bounds__(256) void conv_kernel(const float* __restrict__ src,
                                                   short* __restrict__ dst, int n) {
  int i = blockIdx.x * 256 + threadIdx.x;
  if (i < n) dst[i] = f2bf(src[i]);
}

// dst[n*K + k] = src[k*N + n] * scale   (produce B^T, bf16)
__global__ __launch_bounds__(256) void tconv_kernel(const float* __restrict__ src,
                                                    short* __restrict__ dst,
                                                    int K, int N, float scale) {
  int i = blockIdx.x * 256 + threadIdx.x;
  if (i >= K * N) return;
  int n = i / K, k = i - n * K;
  dst[i] = f2bf(src[(size_t)k * N + n] * scale);
}

// ---------------- layernorm (row per block, D=512) ----------------
__global__ __launch_bounds__(256) void ln_kernel(const float* __restrict__ in,
                                                 const float* __restrict__ g,
                                                 const float* __restrict__ bb,
                                                 short* __restrict__ out) {
  int row = blockIdx.x;
  const float* xr = in + (size_t)row * DB;
  int t = threadIdx.x;
  float x0 = xr[t], x1 = xr[t + 256];
  float s = x0 + x1, s2 = x0 * x0 + x1 * x1;
#pragma unroll
  for (int off = 1; off < 64; off <<= 1) {
    s += __shfl_xor(s, off, 64);
    s2 += __shfl_xor(s2, off, 64);
  }
  __shared__ float r1[4], r2[4];
  int w = t >> 6;
  if ((t & 63) == 0) { r1[w] = s; r2[w] = s2; }
  __syncthreads();
  s = r1[0] + r1[1] + r1[2] + r1[3];
  s2 = r2[0] + r2[1] + r2[2] + r2[3];
  float mean = s * (1.f / DB);
  float var = s2 * (1.f / DB) - mean * mean;
  float rstd = rsqrtf(var + 1e-6f);
  short* orow = out + (size_t)row * DB;
  orow[t] = f2bf((x0 - mean) * rstd * g[t] + bb[t]);
  orow[t + 256] = f2bf((x1 - mean) * rstd * g[t + 256] + bb[t + 256]);
}

// ---------------- GEMM: C[M,N] = A[M,K]bf16 * BT[N,K]bf16 ----------------
template <int KD, int EPI>
__global__ __launch_bounds__(256) void gemm_kernel(
    const short* __restrict__ A, const short* __restrict__ BT,
    const float* __restrict__ bias, const float* __restrict__ resid,
    short* __restrict__ o0, short* __restrict__ o1, short* __restrict__ o2,
    float* __restrict__ of) {
  int tid = threadIdx.x;
  int l = tid & 63, w = tid >> 6;
  int wr = w >> 1, wc = w & 1;
  int lr = l & 15, lq = l >> 4;
  size_t row0 = (size_t)blockIdx.y * 64 + wr * 32;
  size_t col0 = (size_t)blockIdx.x * 64 + wc * 32;

  f32x4 acc[2][2];
#pragma unroll
  for (int a = 0; a < 2; ++a)
#pragma unroll
    for (int b = 0; b < 2; ++b) acc[a][b] = (f32x4){0.f, 0.f, 0.f, 0.f};

  const short* ap = A + (row0 + lr) * KD + lq * 8;
  const short* bp = BT + (col0 + lr) * KD + lq * 8;
#pragma unroll 2
  for (int k0 = 0; k0 < KD; k0 += 32) {
    bf16x8 a0 = *(const bf16x8*)(ap + k0);
    bf16x8 a1 = *(const bf16x8*)(ap + (size_t)16 * KD + k0);
    bf16x8 b0 = *(const bf16x8*)(bp + k0);
    bf16x8 b1 = *(const bf16x8*)(bp + (size_t)16 * KD + k0);
    acc[0][0] = mfma16(a0, b0, acc[0][0]);
    acc[0][1] = mfma16(a0, b1, acc[0][1]);
    acc[1][0] = mfma16(a1, b0, acc[1][0]);
    acc[1][1] = mfma16(a1, b1, acc[1][1]);
  }

#pragma unroll
  for (int a = 0; a < 2; ++a)
#pragma unroll
    for (int b = 0; b < 2; ++b)
#pragma unroll
      for (int r = 0; r < 4; ++r) {
        size_t row = row0 + a * 16 + lq * 4 + r;
        size_t col = col0 + b * 16 + lr;
        float val = acc[a][b][r];
        if (EPI == 0) {
          int sect = (int)(col >> 9);
          int hh = (int)((col >> 6) & 7);
          int d = (int)(col & 63);
          size_t b_ = row >> 11, s_ = row & 2047;
          size_t bh = b_ * HB + hh;
          short bv = f2bf(val);
          if (sect == 0) o0[(bh * SB + s_) * DKB + d] = bv;
          else if (sect == 1) o1[(bh * SB + s_) * DKB + d] = bv;
          else o2[(bh * DKB + d) * SB + s_] = bv;  // V transposed
        } else if (EPI == 1) {
          of[row * DB + col] = resid[row * DB + col] + val + bias[col];
        } else {
          float tv = val + bias[col];
          o0[row * DFB + col] = f2bf(tv > 0.f ? tv : 0.f);
        }
      }
}

// ---------------- fused causal attention with relative positions ----------
// Swapped-operand flash attention: 1 wave = 16 query rows, KVBLK = 64.
// Lane owns q-row (lane&15); scores/softmax/O accumulator all lane-local.
__global__ __launch_bounds__(256) void attn_kernel(
    const short* __restrict__ Q, const short* __restrict__ Kb,
    const short* __restrict__ VT, const short* __restrict__ Eb,
    short* __restrict__ out) {
  __shared__ float band[4][16][86];   // rel band, stride 86 (odd multiple of 2) ~2-way banks
  __shared__ short Pl[4][1024];       // P tile, 16 rows x 128B, XOR-swizzled slots
  int l = threadIdx.x & 63, w = threadIdx.x >> 6;
  int lr = l & 15, lq = l >> 4;
  int tile = blockIdx.x * 4 + w;                 // 4096 waves total
  int bh = tile >> 7;
  int qt = ((tile & 127) + bh * 37) & 127;       // per-CU load balance rotation
  int i0 = qt << 4;
  const short* Qh = Q + (size_t)bh * SB * DKB;
  const short* Kh = Kb + (size_t)bh * SB * DKB;
  const short* Vh = VT + (size_t)bh * DKB * SB;
  const short* Eh = Eb + (size_t)(bh & 7) * SB * DKB;

  bf16x8 qf0 = *(const bf16x8*)(Qh + (size_t)(i0 + lr) * DKB + lq * 8);
  bf16x8 qf1 = *(const bf16x8*)(Qh + (size_t)(i0 + lr) * DKB + 32 + lq * 8);

  const f32x4 zz = {0.f, 0.f, 0.f, 0.f};
  f32x4 acco[4];
#pragma unroll
  for (int dt = 0; dt < 4; ++dt) acco[dt] = zz;
  float mrun = -1e30f, lrun = 0.f;
  float* bd = &band[w][0][0];
  short* pb = &Pl[w][0];

  int imax = i0 + 15;
  for (int j0 = 0; j0 <= imax; j0 += 64) {
    // ---- QK^T swapped: sc[hh] lane holds S[q=lr][k = j0+hh*16+lq*4+r] ----
    f32x4 sc[4];
#pragma unroll
    for (int hh = 0; hh < 4; ++hh) {
      const short* kp = Kh + (size_t)(j0 + hh * 16 + lr) * DKB + lq * 8;
      sc[hh] = mfma16(*(const bf16x8*)kp, qf0, zz);
      sc[hh] = mfma16(*(const bf16x8*)(kp + 32), qf1, sc[hh]);
    }
    // ---- rel band swapped: R[q=lr][t = nt*16+lq*4+r], t in [0,80) ----
    int rbase = SB - 16 - i0 + j0;
#pragma unroll
    for (int nt = 0; nt < 5; ++nt) {
      int er = rbase + nt * 16 + lr;
      er = er < SB ? er : SB - 1;
      const short* ep = Eh + (size_t)er * DKB + lq * 8;
      f32x4 rr = mfma16(*(const bf16x8*)ep, qf0, zz);
      rr = mfma16(*(const bf16x8*)(ep + 32), qf1, rr);
      int bi = lr * 86 + nt * 16 + lq * 4;
      *(f32x2*)(bd + bi) = (f32x2){rr[0], rr[1]};
      *(f32x2*)(bd + bi + 2) = (f32x2){rr[2], rr[3]};
    }
    asm volatile("s_waitcnt lgkmcnt(0)" ::: "memory");
    __builtin_amdgcn_sched_barrier(0);
    // ---- scores + in-lane softmax (lane owns row lr) ----
    float s[4][4];
    float tm = -1e30f;
    int thr = i0 + lr - j0;   // valid iff n <= thr
#pragma unroll
    for (int hh = 0; hh < 4; ++hh)
#pragma unroll
      for (int r = 0; r < 4; ++r) {
        int n = hh * 16 + lq * 4 + r;
        float v = sc[hh][r] + bd[lr * 86 + (n - lr + 15)];
        v = (n <= thr) ? v : -1e30f;
        s[hh][r] = v;
        tm = fmaxf(tm, v);
      }
    tm = fmaxf(tm, __shfl_xor(tm, 16, 64));
    tm = fmaxf(tm, __shfl_xor(tm, 32, 64));
    float mnew = fmaxf(mrun, tm);
    float corr = __expf(mrun - mnew);
    mrun = mnew;
    float rs = 0.f;
#pragma unroll
    for (int hh = 0; hh < 4; ++hh) {
      float p0 = __expf(s[hh][0] - mnew);
      float p1 = __expf(s[hh][1] - mnew);
      float p2 = __expf(s[hh][2] - mnew);
      float p3 = __expf(s[hh][3] - mnew);
      rs += (p0 + p1) + (p2 + p3);
      u32x2 pk = {pack2bf(p0, p1), pack2bf(p2, p3)};
      // logical slot = hh*2 + (lq>>1), physical slot ^= (lr&7); 8B at (lq&1)*8
      int byteoff = lr * 128 + ((((hh << 1) | (lq >> 1)) ^ (lr & 7)) << 4) + ((lq & 1) << 3);
      *(u32x2*)((char*)pb + byteoff) = pk;
    }
    rs += __shfl_xor(rs, 16, 64);
    rs += __shfl_xor(rs, 32, 64);
    lrun = lrun * corr + rs;
#pragma unroll
    for (int dt = 0; dt < 4; ++dt) acco[dt] *= corr;
    asm volatile("s_waitcnt lgkmcnt(0)" ::: "memory");
    __builtin_amdgcn_sched_barrier(0);
    // ---- PV swapped: O^T[d][q] += V^T[d][n] * P^T[n][q] ----
#pragma unroll
    for (int kc = 0; kc < 2; ++kc) {
      bf16x8 pf = *(const bf16x8*)((char*)pb + lr * 128 + ((((kc << 2) | lq) ^ (lr & 7)) << 4));
      __builtin_amdgcn_s_setprio(1);
#pragma unroll
      for (int dt = 0; dt < 4; ++dt) {
        const short* vp = Vh + (size_t)(dt * 16 + lr) * SB + j0 + kc * 32 + lq * 8;
        acco[dt] = mfma16(*(const bf16x8*)vp, pf, acco[dt]);
      }
      __builtin_amdgcn_s_setprio(0);
    }
  }
  // ---- epilogue: lane holds O[q=lr][d = dt*16+lq*4+r] ----
  float inv = 1.f / lrun;
  int b_ = bh >> 3, hd = bh & 7;
  short* orow = out + ((size_t)(b_ * SB + i0 + lr) * DB + hd * 64);
#pragma unroll
  for (int dt = 0; dt < 4; ++dt) {
    s16x4 pkv;
#pragma unroll
    for (int r = 0; r < 4; ++r) pkv[r] = f2bf(acco[dt][r] * inv);
    *(s16x4*)(orow + dt * 16 + lq * 4) = pkv;
  }
}

// ---------------- host ----------------
extern "C" void kernel_launch(void* const* d_in, const int* in_sizes, int n_in,
                              void* d_out, int out_size, void* d_ws, size_t ws_size,
                              hipStream_t stream) {
  const float* x    = (const float*)d_in[0];
  const float* wq   = (const float*)d_in[2];
  const float* wk   = (const float*)d_in[3];
  const float* wv   = (const float*)d_in[4];
  const float* w0   = (const float*)d_in[5];
  const float* b0   = (const float*)d_in[6];
  const float* rel  = (const float*)d_in[7];
  const float* ln1g = (const float*)d_in[8];
  const float* ln1b = (const float*)d_in[9];
  const float* ln2g = (const float*)d_in[10];
  const float* ln2b = (const float*)d_in[11];
  const float* fw1  = (const float*)d_in[12];
  const float* fb1  = (const float*)d_in[13];
  const float* fw2  = (const float*)d_in[14];
  const float* fb2  = (const float*)d_in[15];
  float* outp = (float*)d_out;

  char* ws = (char*)d_ws;
  size_t off = 0;
  auto alloc = [&](size_t bytes) {
    char* p = ws + off;
    off += (bytes + 255) & ~(size_t)255;
    return p;
  };
  short* wqkvT = (short*)alloc((size_t)1536 * 512 * 2);
  short* w0T   = (short*)alloc((size_t)512 * 512 * 2);
  short* fw1T  = (short*)alloc((size_t)2048 * 512 * 2);
  short* fw2T  = (short*)alloc((size_t)512 * 2048 * 2);
  short* relb  = (short*)alloc((size_t)8 * 2048 * 64 * 2);
  short* hbuf  = (short*)alloc((size_t)8192 * 512 * 2);
  short* Qb    = (short*)alloc((size_t)8192 * 512 * 2);
  short* Kbf   = (short*)alloc((size_t)8192 * 512 * 2);
  short* VTb   = (short*)alloc((size_t)8192 * 512 * 2);
  short* attnb = (short*)alloc((size_t)8192 * 512 * 2);
  float* x2    = (float*)alloc((size_t)8192 * 512 * 4);
  short* ff1 = hbuf;
  short* h2  = attnb;

  dim3 blk(256);
  conv_kernel<<<(8 * 2048 * 64 + 255) / 256, blk, 0, stream>>>(rel, relb, 8 * 2048 * 64);
  tconv_kernel<<<(512 * 512 + 255) / 256, blk, 0, stream>>>(wq, wqkvT, 512, 512, 1.f);
  tconv_kernel<<<(512 * 512 + 255) / 256, blk, 0, stream>>>(wk, wqkvT + 512 * 512, 512, 512, 0.125f);
  tconv_kernel<<<(512 * 512 + 255) / 256, blk, 0, stream>>>(wv, wqkvT + 1024 * 512, 512, 512, 1.f);
  tconv_kernel<<<(512 * 512 + 255) / 256, blk, 0, stream>>>(w0, w0T, 512, 512, 1.f);
  tconv_kernel<<<(512 * 2048 + 255) / 256, blk, 0, stream>>>(fw1, fw1T, 512, 2048, 1.f);
  tconv_kernel<<<(512 * 2048 + 255) / 256, blk, 0, stream>>>(fw2, fw2T, 2048, 512, 1.f);

  ln_kernel<<<8192, blk, 0, stream>>>(x, ln1g, ln1b, hbuf);
  gemm_kernel<512, 0><<<dim3(24, 128), blk, 0, stream>>>(hbuf, wqkvT, nullptr, nullptr,
                                                         Qb, Kbf, VTb, nullptr);
  attn_kernel<<<1024, blk, 0, stream>>>(Qb, Kbf, VTb, relb, attnb);
  gemm_kernel<512, 1><<<dim3(8, 128), blk, 0, stream>>>(attnb, w0T, b0, x,
                                                        nullptr, nullptr, nullptr, x2);
  ln_kernel<<<8192, blk, 0, stream>>>(x2, ln2g, ln2b, h2);
  gemm_kernel<512, 2><<<dim3(32, 128), blk, 0, stream>>>(h2, fw1T, fb1, nullptr,
                                                         ff1, nullptr, nullptr, nullptr);
  gemm_kernel<2048, 1><<<dim3(8, 128), blk, 0, stream>>>(ff1, fw2T, fb2, x2,
                                                         nullptr, nullptr, nullptr, outp);
}

// Round 3
// 451.572 us; speedup vs baseline: 2.6241x; 1.5110x over previous
//
#include <hip/hip_runtime.h>
#include <hip/hip_bf16.h>

// Problem constants
#define SB 2048
#define DB 512
#define HB 8
#define DKB 64
#define DFB 2048
#define BATCH 4

typedef __attribute__((ext_vector_type(8))) short bf16x8;
typedef __attribute__((ext_vector_type(4))) float f32x4;
typedef __attribute__((ext_vector_type(2))) float f32x2;
typedef __attribute__((ext_vector_type(2))) unsigned u32x2;
typedef __attribute__((ext_vector_type(4))) short s16x4;

static __device__ __forceinline__ short f2bf(float x) {
  union { float f; unsigned u; } v; v.f = x;
  unsigned r = (v.u + 0x7fffu + ((v.u >> 16) & 1u)) >> 16;
  return (short)(unsigned short)r;
}

static __device__ __forceinline__ unsigned pack2bf(float a, float b) {
  return (unsigned)(unsigned short)f2bf(a) | ((unsigned)(unsigned short)f2bf(b) << 16);
}

static __device__ __forceinline__ f32x4 mfma16(bf16x8 a, bf16x8 b, f32x4 c) {
  return __builtin_amdgcn_mfma_f32_16x16x32_bf16(a, b, c, 0, 0, 0);
}

// async global->LDS, 16B per lane; LDS dest is wave-uniform base + lane*16
static __device__ __forceinline__ void gload_lds16(const short* g, short* l) {
  __builtin_amdgcn_global_load_lds(
      (const __attribute__((address_space(1))) unsigned*)g,
      (__attribute__((address_space(3))) unsigned*)l, 16, 0, 0);
}

// ---------------- weight prep ----------------
__global__ __launch_bounds__(256) void conv_kernel(const float* __restrict__ src,
                                                   short* __restrict__ dst, int n) {
  int i = blockIdx.x * 256 + threadIdx.x;
  if (i < n) dst[i] = f2bf(src[i]);
}

// dst[n*K + k] = src[k*N + n] * scale   (produce B^T, bf16)
__global__ __launch_bounds__(256) void tconv_kernel(const float* __restrict__ src,
                                                    short* __restrict__ dst,
                                                    int K, int N, float scale) {
  int i = blockIdx.x * 256 + threadIdx.x;
  if (i >= K * N) return;
  int n = i / K, k = i - n * K;
  dst[i] = f2bf(src[(size_t)k * N + n] * scale);
}

// ---------------- layernorm: one wave per 512-elem row ----------------
__global__ __launch_bounds__(256) void ln_kernel(const float* __restrict__ in,
                                                 const float* __restrict__ g,
                                                 const float* __restrict__ bb,
                                                 short* __restrict__ out) {
  int w = threadIdx.x >> 6, l = threadIdx.x & 63;
  size_t row = (size_t)blockIdx.x * 4 + w;
  const float* xr = in + row * DB;
  f32x4 v0 = *(const f32x4*)(xr + l * 8);
  f32x4 v1 = *(const f32x4*)(xr + l * 8 + 4);
  float s = (v0[0] + v0[1]) + (v0[2] + v0[3]) + (v1[0] + v1[1]) + (v1[2] + v1[3]);
  float s2 = (v0[0] * v0[0] + v0[1] * v0[1]) + (v0[2] * v0[2] + v0[3] * v0[3]) +
             (v1[0] * v1[0] + v1[1] * v1[1]) + (v1[2] * v1[2] + v1[3] * v1[3]);
#pragma unroll
  for (int off = 1; off < 64; off <<= 1) {
    s += __shfl_xor(s, off, 64);
    s2 += __shfl_xor(s2, off, 64);
  }
  float mean = s * (1.f / DB);
  float var = s2 * (1.f / DB) - mean * mean;
  float rstd = rsqrtf(var + 1e-6f);
  f32x4 g0 = *(const f32x4*)(g + l * 8);
  f32x4 g1 = *(const f32x4*)(g + l * 8 + 4);
  f32x4 b0 = *(const f32x4*)(bb + l * 8);
  f32x4 b1 = *(const f32x4*)(bb + l * 8 + 4);
  bf16x8 ov;
#pragma unroll
  for (int e = 0; e < 4; ++e) ov[e] = f2bf((v0[e] - mean) * rstd * g0[e] + b0[e]);
#pragma unroll
  for (int e = 0; e < 4; ++e) ov[4 + e] = f2bf((v1[e] - mean) * rstd * g1[e] + b1[e]);
  *(bf16x8*)(out + row * DB + l * 8) = ov;
}

// ---------------- GEMM: C[M,N] = A[M,K]bf16 * BT[N,K]bf16 ----------------
// m97 structure: 128x128 tile, BK=32, 4 waves (2x2), global_load_lds staging,
// linear LDS [128][32], ds_read_b128 fragments, 4x4 acc per wave.
template <int KD, int EPI>
__global__ __launch_bounds__(256) void gemm_kernel(
    const short* __restrict__ A, const short* __restrict__ BT,
    const float* __restrict__ bias, const float* __restrict__ resid,
    short* __restrict__ o0, short* __restrict__ o1, short* __restrict__ o2,
    float* __restrict__ of) {
  __shared__ short As[4096];  // 128 rows x 32 k
  __shared__ short Bs[4096];
  int tid = threadIdx.x;
  int l = tid & 63, w = tid >> 6;
  int wr = w >> 1, wc = w & 1;
  int lr = l & 15, lq = l >> 4;
  int row0 = blockIdx.y * 128;
  int col0 = blockIdx.x * 128;

  f32x4 acc[4][4];
#pragma unroll
  for (int a = 0; a < 4; ++a)
#pragma unroll
    for (int b = 0; b < 4; ++b) acc[a][b] = (f32x4){0.f, 0.f, 0.f, 0.f};

  // staging: thread tid covers row tid/4 (and +64), k-chunk (tid&3)*8
  const short* gA = A + (size_t)(row0 + (tid >> 2)) * KD + (tid & 3) * 8;
  const short* gB = BT + (size_t)(col0 + (tid >> 2)) * KD + (tid & 3) * 8;
  const size_t step64 = (size_t)64 * KD;
  short* lA = As + w * 512;  // wave w stages rows w*16..w*16+15 (1KB)
  short* lB = Bs + w * 512;

  for (int k0 = 0; k0 < KD; k0 += 32) {
    gload_lds16(gA + k0, lA);
    gload_lds16(gA + step64 + k0, lA + 2048);
    gload_lds16(gB + k0, lB);
    gload_lds16(gB + step64 + k0, lB + 2048);
    __syncthreads();  // drains vmcnt -> LDS tile ready
    bf16x8 af[4], bfv[4];
#pragma unroll
    for (int a = 0; a < 4; ++a)
      af[a] = *(const bf16x8*)(As + (wr * 64 + a * 16 + lr) * 32 + lq * 8);
#pragma unroll
    for (int b = 0; b < 4; ++b)
      bfv[b] = *(const bf16x8*)(Bs + (wc * 64 + b * 16 + lr) * 32 + lq * 8);
#pragma unroll
    for (int a = 0; a < 4; ++a)
#pragma unroll
      for (int b = 0; b < 4; ++b)
        acc[a][b] = mfma16(af[a], bfv[b], acc[a][b]);
    __syncthreads();  // all reads done before next stage overwrites
  }

#pragma unroll
  for (int a = 0; a < 4; ++a)
#pragma unroll
    for (int b = 0; b < 4; ++b)
#pragma unroll
      for (int r = 0; r < 4; ++r) {
        size_t row = (size_t)row0 + wr * 64 + a * 16 + lq * 4 + r;
        size_t col = (size_t)col0 + wc * 64 + b * 16 + lr;
        float val = acc[a][b][r];
        if (EPI == 0) {
          int sect = (int)(col >> 9);
          int hh = (int)((col >> 6) & 7);
          int d = (int)(col & 63);
          size_t b_ = row >> 11, s_ = row & 2047;
          size_t bh = b_ * HB + hh;
          short bv = f2bf(val);
          if (sect == 0) o0[(bh * SB + s_) * DKB + d] = bv;
          else if (sect == 1) o1[(bh * SB + s_) * DKB + d] = bv;
          else o2[(bh * DKB + d) * SB + s_] = bv;  // V transposed
        } else if (EPI == 1) {
          of[row * DB + col] = resid[row * DB + col] + val + bias[col];
        } else {
          float tv = val + bias[col];
          o0[row * DFB + col] = f2bf(tv > 0.f ? tv : 0.f);
        }
      }
}

// ---------------- fused causal attention with relative positions ----------
// Swapped-operand flash attention: 1 wave = 16 query rows, KVBLK = 64.
__global__ __launch_bounds__(256) void attn_kernel(
    const short* __restrict__ Q, const short* __restrict__ Kb,
    const short* __restrict__ VT, const short* __restrict__ Eb,
    short* __restrict__ out) {
  __shared__ float band[4][16][86];
  __shared__ short Pl[4][1024];
  int l = threadIdx.x & 63, w = threadIdx.x >> 6;
  int lr = l & 15, lq = l >> 4;
  int tile = blockIdx.x * 4 + w;
  int bh = tile >> 7;
  int qt = ((tile & 127) + bh * 37) & 127;
  int i0 = qt << 4;
  const short* Qh = Q + (size_t)bh * SB * DKB;
  const short* Kh = Kb + (size_t)bh * SB * DKB;
  const short* Vh = VT + (size_t)bh * DKB * SB;
  const short* Eh = Eb + (size_t)(bh & 7) * SB * DKB;

  bf16x8 qf0 = *(const bf16x8*)(Qh + (size_t)(i0 + lr) * DKB + lq * 8);
  bf16x8 qf1 = *(const bf16x8*)(Qh + (size_t)(i0 + lr) * DKB + 32 + lq * 8);

  const f32x4 zz = {0.f, 0.f, 0.f, 0.f};
  f32x4 acco[4];
#pragma unroll
  for (int dt = 0; dt < 4; ++dt) acco[dt] = zz;
  float mrun = -1e30f, lrun = 0.f;
  float* bd = &band[w][0][0];
  short* pb = &Pl[w][0];

  int imax = i0 + 15;
  for (int j0 = 0; j0 <= imax; j0 += 64) {
    f32x4 sc[4];
#pragma unroll
    for (int hh = 0; hh < 4; ++hh) {
      const short* kp = Kh + (size_t)(j0 + hh * 16 + lr) * DKB + lq * 8;
      sc[hh] = mfma16(*(const bf16x8*)kp, qf0, zz);
      sc[hh] = mfma16(*(const bf16x8*)(kp + 32), qf1, sc[hh]);
    }
    int rbase = SB - 16 - i0 + j0;
#pragma unroll
    for (int nt = 0; nt < 5; ++nt) {
      int er = rbase + nt * 16 + lr;
      er = er < SB ? er : SB - 1;
      const short* ep = Eh + (size_t)er * DKB + lq * 8;
      f32x4 rr = mfma16(*(const bf16x8*)ep, qf0, zz);
      rr = mfma16(*(const bf16x8*)(ep + 32), qf1, rr);
      int bi = lr * 86 + nt * 16 + lq * 4;
      *(f32x2*)(bd + bi) = (f32x2){rr[0], rr[1]};
      *(f32x2*)(bd + bi + 2) = (f32x2){rr[2], rr[3]};
    }
    asm volatile("s_waitcnt lgkmcnt(0)" ::: "memory");
    __builtin_amdgcn_sched_barrier(0);
    float s[4][4];
    float tm = -1e30f;
    int thr = i0 + lr - j0;
#pragma unroll
    for (int hh = 0; hh < 4; ++hh)
#pragma unroll
      for (int r = 0; r < 4; ++r) {
        int n = hh * 16 + lq * 4 + r;
        float v = sc[hh][r] + bd[lr * 86 + (n - lr + 15)];
        v = (n <= thr) ? v : -1e30f;
        s[hh][r] = v;
        tm = fmaxf(tm, v);
      }
    tm = fmaxf(tm, __shfl_xor(tm, 16, 64));
    tm = fmaxf(tm, __shfl_xor(tm, 32, 64));
    float mnew = fmaxf(mrun, tm);
    float corr = __expf(mrun - mnew);
    mrun = mnew;
    float rs = 0.f;
#pragma unroll
    for (int hh = 0; hh < 4; ++hh) {
      float p0 = __expf(s[hh][0] - mnew);
      float p1 = __expf(s[hh][1] - mnew);
      float p2 = __expf(s[hh][2] - mnew);
      float p3 = __expf(s[hh][3] - mnew);
      rs += (p0 + p1) + (p2 + p3);
      u32x2 pk = {pack2bf(p0, p1), pack2bf(p2, p3)};
      int byteoff = lr * 128 + ((((hh << 1) | (lq >> 1)) ^ (lr & 7)) << 4) + ((lq & 1) << 3);
      *(u32x2*)((char*)pb + byteoff) = pk;
    }
    rs += __shfl_xor(rs, 16, 64);
    rs += __shfl_xor(rs, 32, 64);
    lrun = lrun * corr + rs;
#pragma unroll
    for (int dt = 0; dt < 4; ++dt) acco[dt] *= corr;
    asm volatile("s_waitcnt lgkmcnt(0)" ::: "memory");
    __builtin_amdgcn_sched_barrier(0);
#pragma unroll
    for (int kc = 0; kc < 2; ++kc) {
      bf16x8 pf = *(const bf16x8*)((char*)pb + lr * 128 + ((((kc << 2) | lq) ^ (lr & 7)) << 4));
      __builtin_amdgcn_s_setprio(1);
#pragma unroll
      for (int dt = 0; dt < 4; ++dt) {
        const short* vp = Vh + (size_t)(dt * 16 + lr) * SB + j0 + kc * 32 + lq * 8;
        acco[dt] = mfma16(*(const bf16x8*)vp, pf, acco[dt]);
      }
      __builtin_amdgcn_s_setprio(0);
    }
  }
  float inv = 1.f / lrun;
  int b_ = bh >> 3, hd = bh & 7;
  short* orow = out + ((size_t)(b_ * SB + i0 + lr) * DB + hd * 64);
#pragma unroll
  for (int dt = 0; dt < 4; ++dt) {
    s16x4 pkv;
#pragma unroll
    for (int r = 0; r < 4; ++r) pkv[r] = f2bf(acco[dt][r] * inv);
    *(s16x4*)(orow + dt * 16 + lq * 4) = pkv;
  }
}

// ---------------- host ----------------
extern "C" void kernel_launch(void* const* d_in, const int* in_sizes, int n_in,
                              void* d_out, int out_size, void* d_ws, size_t ws_size,
                              hipStream_t stream) {
  const float* x    = (const float*)d_in[0];
  const float* wq   = (const float*)d_in[2];
  const float* wk   = (const float*)d_in[3];
  const float* wv   = (const float*)d_in[4];
  const float* w0   = (const float*)d_in[5];
  const float* b0   = (const float*)d_in[6];
  const float* rel  = (const float*)d_in[7];
  const float* ln1g = (const float*)d_in[8];
  const float* ln1b = (const float*)d_in[9];
  const float* ln2g = (const float*)d_in[10];
  const float* ln2b = (const float*)d_in[11];
  const float* fw1  = (const float*)d_in[12];
  const float* fb1  = (const float*)d_in[13];
  const float* fw2  = (const float*)d_in[14];
  const float* fb2  = (const float*)d_in[15];
  float* outp = (float*)d_out;

  char* ws = (char*)d_ws;
  size_t off = 0;
  auto alloc = [&](size_t bytes) {
    char* p = ws + off;
    off += (bytes + 255) & ~(size_t)255;
    return p;
  };
  short* wqkvT = (short*)alloc((size_t)1536 * 512 * 2);
  short* w0T   = (short*)alloc((size_t)512 * 512 * 2);
  short* fw1T  = (short*)alloc((size_t)2048 * 512 * 2);
  short* fw2T  = (short*)alloc((size_t)512 * 2048 * 2);
  short* relb  = (short*)alloc((size_t)8 * 2048 * 64 * 2);
  short* hbuf  = (short*)alloc((size_t)8192 * 512 * 2);
  short* Qb    = (short*)alloc((size_t)8192 * 512 * 2);
  short* Kbf   = (short*)alloc((size_t)8192 * 512 * 2);
  short* VTb   = (short*)alloc((size_t)8192 * 512 * 2);
  short* attnb = (short*)alloc((size_t)8192 * 512 * 2);
  float* x2    = (float*)alloc((size_t)8192 * 512 * 4);
  short* ff1 = hbuf;
  short* h2  = attnb;

  dim3 blk(256);
  conv_kernel<<<(8 * 2048 * 64 + 255) / 256, blk, 0, stream>>>(rel, relb, 8 * 2048 * 64);
  tconv_kernel<<<(512 * 512 + 255) / 256, blk, 0, stream>>>(wq, wqkvT, 512, 512, 1.f);
  tconv_kernel<<<(512 * 512 + 255) / 256, blk, 0, stream>>>(wk, wqkvT + 512 * 512, 512, 512, 0.125f);
  tconv_kernel<<<(512 * 512 + 255) / 256, blk, 0, stream>>>(wv, wqkvT + 1024 * 512, 512, 512, 1.f);
  tconv_kernel<<<(512 * 512 + 255) / 256, blk, 0, stream>>>(w0, w0T, 512, 512, 1.f);
  tconv_kernel<<<(512 * 2048 + 255) / 256, blk, 0, stream>>>(fw1, fw1T, 512, 2048, 1.f);
  tconv_kernel<<<(512 * 2048 + 255) / 256, blk, 0, stream>>>(fw2, fw2T, 2048, 512, 1.f);

  ln_kernel<<<2048, blk, 0, stream>>>(x, ln1g, ln1b, hbuf);
  gemm_kernel<512, 0><<<dim3(12, 64), blk, 0, stream>>>(hbuf, wqkvT, nullptr, nullptr,
                                                        Qb, Kbf, VTb, nullptr);
  attn_kernel<<<1024, blk, 0, stream>>>(Qb, Kbf, VTb, relb, attnb);
  gemm_kernel<512, 1><<<dim3(4, 64), blk, 0, stream>>>(attnb, w0T, b0, x,
                                                       nullptr, nullptr, nullptr, x2);
  ln_kernel<<<2048, blk, 0, stream>>>(x2, ln2g, ln2b, h2);
  gemm_kernel<512, 2><<<dim3(16, 64), blk, 0, stream>>>(h2, fw1T, fb1, nullptr,
                                                        ff1, nullptr, nullptr, nullptr);
  gemm_kernel<2048, 1><<<dim3(4, 64), blk, 0, stream>>>(ff1, fw2T, fb2, x2,
                                                        nullptr, nullptr, nullptr, outp);
}

// Round 4
// 342.918 us; speedup vs baseline: 3.4556x; 1.3169x over previous
//
#include <hip/hip_runtime.h>
#include <hip/hip_bf16.h>

// Problem constants
#define SB 2048
#define DB 512
#define HB 8
#define DKB 64
#define DFB 2048
#define BATCH 4

typedef __attribute__((ext_vector_type(8))) short bf16x8;
typedef __attribute__((ext_vector_type(4))) float f32x4;
typedef __attribute__((ext_vector_type(2))) float f32x2;
typedef __attribute__((ext_vector_type(2))) unsigned u32x2;
typedef __attribute__((ext_vector_type(4))) short s16x4;

static __device__ __forceinline__ short f2bf(float x) {
  union { float f; unsigned u; } v; v.f = x;
  unsigned r = (v.u + 0x7fffu + ((v.u >> 16) & 1u)) >> 16;
  return (short)(unsigned short)r;
}

static __device__ __forceinline__ unsigned pack2bf(float a, float b) {
  return (unsigned)(unsigned short)f2bf(a) | ((unsigned)(unsigned short)f2bf(b) << 16);
}

static __device__ __forceinline__ f32x4 mfma16(bf16x8 a, bf16x8 b, f32x4 c) {
  return __builtin_amdgcn_mfma_f32_16x16x32_bf16(a, b, c, 0, 0, 0);
}

// async global->LDS, 16B per lane; LDS dest is wave-uniform base + lane*16
static __device__ __forceinline__ void gload_lds16(const short* g, short* l) {
  __builtin_amdgcn_global_load_lds(
      (const __attribute__((address_space(1))) unsigned*)g,
      (__attribute__((address_space(3))) unsigned*)l, 16, 0, 0);
}

// ---------------- weight prep ----------------
__global__ __launch_bounds__(256) void conv_kernel(const float* __restrict__ src,
                                                   short* __restrict__ dst, int n) {
  int i = blockIdx.x * 256 + threadIdx.x;
  if (i < n) dst[i] = f2bf(src[i]);
}

// dst[n*K + k] = src[k*N + n] * scale   (produce B^T, bf16)
__global__ __launch_bounds__(256) void tconv_kernel(const float* __restrict__ src,
                                                    short* __restrict__ dst,
                                                    int K, int N, float scale) {
  int i = blockIdx.x * 256 + threadIdx.x;
  if (i >= K * N) return;
  int n = i / K, k = i - n * K;
  dst[i] = f2bf(src[(size_t)k * N + n] * scale);
}

// ---------------- layernorm: one wave per 512-elem row ----------------
__global__ __launch_bounds__(256) void ln_kernel(const float* __restrict__ in,
                                                 const float* __restrict__ g,
                                                 const float* __restrict__ bb,
                                                 short* __restrict__ out) {
  int w = threadIdx.x >> 6, l = threadIdx.x & 63;
  size_t row = (size_t)blockIdx.x * 4 + w;
  const float* xr = in + row * DB;
  f32x4 v0 = *(const f32x4*)(xr + l * 8);
  f32x4 v1 = *(const f32x4*)(xr + l * 8 + 4);
  float s = (v0[0] + v0[1]) + (v0[2] + v0[3]) + (v1[0] + v1[1]) + (v1[2] + v1[3]);
  float s2 = (v0[0] * v0[0] + v0[1] * v0[1]) + (v0[2] * v0[2] + v0[3] * v0[3]) +
             (v1[0] * v1[0] + v1[1] * v1[1]) + (v1[2] * v1[2] + v1[3] * v1[3]);
#pragma unroll
  for (int off = 1; off < 64; off <<= 1) {
    s += __shfl_xor(s, off, 64);
    s2 += __shfl_xor(s2, off, 64);
  }
  float mean = s * (1.f / DB);
  float var = s2 * (1.f / DB) - mean * mean;
  float rstd = rsqrtf(var + 1e-6f);
  f32x4 g0 = *(const f32x4*)(g + l * 8);
  f32x4 g1 = *(const f32x4*)(g + l * 8 + 4);
  f32x4 b0 = *(const f32x4*)(bb + l * 8);
  f32x4 b1 = *(const f32x4*)(bb + l * 8 + 4);
  bf16x8 ov;
#pragma unroll
  for (int e = 0; e < 4; ++e) ov[e] = f2bf((v0[e] - mean) * rstd * g0[e] + b0[e]);
#pragma unroll
  for (int e = 0; e < 4; ++e) ov[4 + e] = f2bf((v1[e] - mean) * rstd * g1[e] + b1[e]);
  *(bf16x8*)(out + row * DB + l * 8) = ov;
}

// ---------------- GEMM: C[M,N] = A[M,K]bf16 * BT[N,K]bf16 ----------------
// m97 structure: 128x128 tile, BK=32, 4 waves (2x2), global_load_lds staging.
template <int KD, int EPI>
__global__ __launch_bounds__(256) void gemm_kernel(
    const short* __restrict__ A, const short* __restrict__ BT,
    const float* __restrict__ bias, const float* __restrict__ resid,
    short* __restrict__ o0, short* __restrict__ o1, short* __restrict__ o2,
    float* __restrict__ of) {
  __shared__ short As[4096];  // 128 rows x 32 k
  __shared__ short Bs[4096];
  int tid = threadIdx.x;
  int l = tid & 63, w = tid >> 6;
  int wr = w >> 1, wc = w & 1;
  int lr = l & 15, lq = l >> 4;
  int row0 = blockIdx.y * 128;
  int col0 = blockIdx.x * 128;

  f32x4 acc[4][4];
#pragma unroll
  for (int a = 0; a < 4; ++a)
#pragma unroll
    for (int b = 0; b < 4; ++b) acc[a][b] = (f32x4){0.f, 0.f, 0.f, 0.f};

  const short* gA = A + (size_t)(row0 + (tid >> 2)) * KD + (tid & 3) * 8;
  const short* gB = BT + (size_t)(col0 + (tid >> 2)) * KD + (tid & 3) * 8;
  const size_t step64 = (size_t)64 * KD;
  short* lA = As + w * 512;
  short* lB = Bs + w * 512;

  for (int k0 = 0; k0 < KD; k0 += 32) {
    gload_lds16(gA + k0, lA);
    gload_lds16(gA + step64 + k0, lA + 2048);
    gload_lds16(gB + k0, lB);
    gload_lds16(gB + step64 + k0, lB + 2048);
    __syncthreads();
    bf16x8 af[4], bfv[4];
#pragma unroll
    for (int a = 0; a < 4; ++a)
      af[a] = *(const bf16x8*)(As + (wr * 64 + a * 16 + lr) * 32 + lq * 8);
#pragma unroll
    for (int b = 0; b < 4; ++b)
      bfv[b] = *(const bf16x8*)(Bs + (wc * 64 + b * 16 + lr) * 32 + lq * 8);
#pragma unroll
    for (int a = 0; a < 4; ++a)
#pragma unroll
      for (int b = 0; b < 4; ++b)
        acc[a][b] = mfma16(af[a], bfv[b], acc[a][b]);
    __syncthreads();
  }

#pragma unroll
  for (int a = 0; a < 4; ++a)
#pragma unroll
    for (int b = 0; b < 4; ++b)
#pragma unroll
      for (int r = 0; r < 4; ++r) {
        size_t row = (size_t)row0 + wr * 64 + a * 16 + lq * 4 + r;
        size_t col = (size_t)col0 + wc * 64 + b * 16 + lr;
        float val = acc[a][b][r];
        if (EPI == 0) {
          int sect = (int)(col >> 9);
          int hh = (int)((col >> 6) & 7);
          int d = (int)(col & 63);
          size_t b_ = row >> 11, s_ = row & 2047;
          size_t bh = b_ * HB + hh;
          short bv = f2bf(val);
          if (sect == 0) o0[(bh * SB + s_) * DKB + d] = bv;
          else if (sect == 1) o1[(bh * SB + s_) * DKB + d] = bv;
          else o2[(bh * DKB + d) * SB + s_] = bv;  // V transposed
        } else if (EPI == 1) {
          of[row * DB + col] = resid[row * DB + col] + val + bias[col];
        } else {
          float tv = val + bias[col];
          o0[row * DFB + col] = f2bf(tv > 0.f ? tv : 0.f);
        }
      }
}

// ---------------- attention helpers ----------------
static __device__ __forceinline__ void sm_step(const f32x4* sc, const float* bd,
                                               short* pb, f32x4* acc,
                                               float& mrun, float& lrun,
                                               int i0, int j0, int lr, int lq) {
  int thr = i0 + lr - j0;
  float s[4][4];
  float tm = -1e30f;
  if (j0 + 63 > i0) {
#pragma unroll
    for (int hh = 0; hh < 4; ++hh)
#pragma unroll
      for (int r = 0; r < 4; ++r) {
        int n = hh * 16 + lq * 4 + r;
        float v = sc[hh][r] + bd[lr * 86 + (n - lr + 15)];
        v = (n <= thr) ? v : -1e30f;
        s[hh][r] = v;
        tm = fmaxf(tm, v);
      }
  } else {
#pragma unroll
    for (int hh = 0; hh < 4; ++hh)
#pragma unroll
      for (int r = 0; r < 4; ++r) {
        float v = sc[hh][r] + bd[lr * 86 + (hh * 16 + lq * 4 + r - lr + 15)];
        s[hh][r] = v;
        tm = fmaxf(tm, v);
      }
  }
  tm = fmaxf(tm, __shfl_xor(tm, 16, 64));
  tm = fmaxf(tm, __shfl_xor(tm, 32, 64));
  float mnew = fmaxf(mrun, tm);
  float corr = __expf(mrun - mnew);
  mrun = mnew;
  float rs = 0.f;
#pragma unroll
  for (int hh = 0; hh < 4; ++hh) {
    float p0 = __expf(s[hh][0] - mnew);
    float p1 = __expf(s[hh][1] - mnew);
    float p2 = __expf(s[hh][2] - mnew);
    float p3 = __expf(s[hh][3] - mnew);
    rs += (p0 + p1) + (p2 + p3);
    u32x2 pk = {pack2bf(p0, p1), pack2bf(p2, p3)};
    int byteoff = lr * 128 + ((((hh << 1) | (lq >> 1)) ^ (lr & 7)) << 4) + ((lq & 1) << 3);
    *(u32x2*)((char*)pb + byteoff) = pk;
  }
  rs += __shfl_xor(rs, 16, 64);
  rs += __shfl_xor(rs, 32, 64);
  lrun = lrun * corr + rs;
#pragma unroll
  for (int dt = 0; dt < 4; ++dt) acc[dt] *= corr;
}

static __device__ __forceinline__ void pv_step(const short* pb, const bf16x8* vf,
                                               f32x4* acc, int lr, int lq) {
#pragma unroll
  for (int kc = 0; kc < 2; ++kc) {
    bf16x8 pf = *(const bf16x8*)((const char*)pb + lr * 128 +
                                 ((((kc << 2) | lq) ^ (lr & 7)) << 4));
    __builtin_amdgcn_s_setprio(1);
#pragma unroll
    for (int dt = 0; dt < 4; ++dt)
      acc[dt] = mfma16(vf[kc * 4 + dt], pf, acc[dt]);
    __builtin_amdgcn_s_setprio(0);
  }
}

static __device__ __forceinline__ void attn_out(const f32x4* acc, float lrun,
                                                short* out, int bh, int i0,
                                                int lr, int lq) {
  float inv = 1.f / lrun;
  int b_ = bh >> 3, hd = bh & 7;
  short* orow = out + ((size_t)(b_ * SB + i0 + lr) * DB + hd * 64);
#pragma unroll
  for (int dt = 0; dt < 4; ++dt) {
    s16x4 pkv;
#pragma unroll
    for (int r = 0; r < 4; ++r) pkv[r] = f2bf(acc[dt][r] * inv);
    *(s16x4*)(orow + dt * 16 + lq * 4) = pkv;
  }
}

// ---------------- fused causal attention with relative positions ----------
// Pair-tile waves: each wave owns q-tiles qta and 127-qta of one (b,h) ->
// constant total work per wave, shared K/V loads, two independent chains.
// XCD swizzle: bid&7 selects XCD group; 4 heads per XCD -> L2-resident K/V/E.
__global__ __launch_bounds__(256, 2) void attn_kernel(
    const short* __restrict__ Q, const short* __restrict__ Kb,
    const short* __restrict__ VT, const short* __restrict__ Eb,
    short* __restrict__ out) {
  __shared__ float band[4][2][16][86];
  __shared__ short Pl[4][2][1024];
  int tid = threadIdx.x;
  int l = tid & 63, w = tid >> 6;
  int lr = l & 15, lq = l >> 4;
  int bid = blockIdx.x;                  // 512 blocks
  int sub = bid >> 3;                    // [0,64)
  int bh = (bid & 7) * 4 + (sub >> 4);   // 4 heads per XCD slot
  int qta = (sub & 15) + (w << 4);       // [0,64)
  int qtb = 127 - qta;
  int i0a = qta << 4, i0b = qtb << 4;
  const short* Qh = Q + (size_t)bh * SB * DKB;
  const short* Kh = Kb + (size_t)bh * SB * DKB;
  const short* Vh = VT + (size_t)bh * DKB * SB;
  const short* Eh = Eb + (size_t)(bh & 7) * SB * DKB;

  bf16x8 qa0 = *(const bf16x8*)(Qh + (size_t)(i0a + lr) * DKB + lq * 8);
  bf16x8 qa1 = *(const bf16x8*)(Qh + (size_t)(i0a + lr) * DKB + 32 + lq * 8);
  bf16x8 qb0 = *(const bf16x8*)(Qh + (size_t)(i0b + lr) * DKB + lq * 8);
  bf16x8 qb1 = *(const bf16x8*)(Qh + (size_t)(i0b + lr) * DKB + 32 + lq * 8);

  const f32x4 zz = {0.f, 0.f, 0.f, 0.f};
  f32x4 accA[4], accB[4];
#pragma unroll
  for (int dt = 0; dt < 4; ++dt) { accA[dt] = zz; accB[dt] = zz; }
  float mA = -1e30f, lA = 0.f, mB = -1e30f, lB = 0.f;
  float* bdA = &band[w][0][0][0];
  float* bdB = &band[w][1][0][0];
  short* pbA = &Pl[w][0][0];
  short* pbB = &Pl[w][1][0];
  int imaxA = i0a + 15, imaxB = i0b + 15;

  for (int j0 = 0; j0 <= imaxB; j0 += 64) {
    bool actA = (j0 <= imaxA);
    // ---- K fragments (shared by both chains) + QK^T ----
    bf16x8 kf[8];
#pragma unroll
    for (int hh = 0; hh < 4; ++hh) {
      const short* kp = Kh + (size_t)(j0 + hh * 16 + lr) * DKB + lq * 8;
      kf[hh * 2] = *(const bf16x8*)kp;
      kf[hh * 2 + 1] = *(const bf16x8*)(kp + 32);
    }
    f32x4 scB[4], scA[4];
#pragma unroll
    for (int hh = 0; hh < 4; ++hh)
      scB[hh] = mfma16(kf[hh * 2 + 1], qb1, mfma16(kf[hh * 2], qb0, zz));
    if (actA) {
#pragma unroll
      for (int hh = 0; hh < 4; ++hh)
        scA[hh] = mfma16(kf[hh * 2 + 1], qa1, mfma16(kf[hh * 2], qa0, zz));
    }
    // ---- rel bands (per chain) ----
    {
      int rb = SB - 16 - i0b + j0;
#pragma unroll
      for (int nt = 0; nt < 5; ++nt) {
        int er = rb + nt * 16 + lr;
        er = er < SB ? er : SB - 1;
        const short* ep = Eh + (size_t)er * DKB + lq * 8;
        f32x4 rr = mfma16(*(const bf16x8*)(ep + 32), qb1,
                          mfma16(*(const bf16x8*)ep, qb0, zz));
        int bi = lr * 86 + nt * 16 + lq * 4;
        *(f32x2*)(bdB + bi) = (f32x2){rr[0], rr[1]};
        *(f32x2*)(bdB + bi + 2) = (f32x2){rr[2], rr[3]};
      }
    }
    if (actA) {
      int rb = SB - 16 - i0a + j0;
#pragma unroll
      for (int nt = 0; nt < 5; ++nt) {
        int er = rb + nt * 16 + lr;
        er = er < SB ? er : SB - 1;
        const short* ep = Eh + (size_t)er * DKB + lq * 8;
        f32x4 rr = mfma16(*(const bf16x8*)(ep + 32), qa1,
                          mfma16(*(const bf16x8*)ep, qa0, zz));
        int bi = lr * 86 + nt * 16 + lq * 4;
        *(f32x2*)(bdA + bi) = (f32x2){rr[0], rr[1]};
        *(f32x2*)(bdA + bi + 2) = (f32x2){rr[2], rr[3]};
      }
    }
    // ---- V prefetch (shared; latency hides under softmax VALU) ----
    bf16x8 vf[8];
#pragma unroll
    for (int kc = 0; kc < 2; ++kc)
#pragma unroll
      for (int dt = 0; dt < 4; ++dt)
        vf[kc * 4 + dt] =
            *(const bf16x8*)(Vh + (size_t)(dt * 16 + lr) * SB + j0 + kc * 32 + lq * 8);
    // ---- softmax per chain ----
    sm_step(scB, bdB, pbB, accB, mB, lB, i0b, j0, lr, lq);
    if (actA) sm_step(scA, bdA, pbA, accA, mA, lA, i0a, j0, lr, lq);
    // ---- PV per chain ----
    pv_step(pbB, vf, accB, lr, lq);
    if (actA) pv_step(pbA, vf, accA, lr, lq);
  }
  attn_out(accB, lB, out, bh, i0b, lr, lq);
  attn_out(accA, lA, out, bh, i0a, lr, lq);
}

// ---------------- host ----------------
extern "C" void kernel_launch(void* const* d_in, const int* in_sizes, int n_in,
                              void* d_out, int out_size, void* d_ws, size_t ws_size,
                              hipStream_t stream) {
  const float* x    = (const float*)d_in[0];
  const float* wq   = (const float*)d_in[2];
  const float* wk   = (const float*)d_in[3];
  const float* wv   = (const float*)d_in[4];
  const float* w0   = (const float*)d_in[5];
  const float* b0   = (const float*)d_in[6];
  const float* rel  = (const float*)d_in[7];
  const float* ln1g = (const float*)d_in[8];
  const float* ln1b = (const float*)d_in[9];
  const float* ln2g = (const float*)d_in[10];
  const float* ln2b = (const float*)d_in[11];
  const float* fw1  = (const float*)d_in[12];
  const float* fb1  = (const float*)d_in[13];
  const float* fw2  = (const float*)d_in[14];
  const float* fb2  = (const float*)d_in[15];
  float* outp = (float*)d_out;

  char* ws = (char*)d_ws;
  size_t off = 0;
  auto alloc = [&](size_t bytes) {
    char* p = ws + off;
    off += (bytes + 255) & ~(size_t)255;
    return p;
  };
  short* wqkvT = (short*)alloc((size_t)1536 * 512 * 2);
  short* w0T   = (short*)alloc((size_t)512 * 512 * 2);
  short* fw1T  = (short*)alloc((size_t)2048 * 512 * 2);
  short* fw2T  = (short*)alloc((size_t)512 * 2048 * 2);
  short* relb  = (short*)alloc((size_t)8 * 2048 * 64 * 2);
  short* hbuf  = (short*)alloc((size_t)8192 * 512 * 2);
  short* Qb    = (short*)alloc((size_t)8192 * 512 * 2);
  short* Kbf   = (short*)alloc((size_t)8192 * 512 * 2);
  short* VTb   = (short*)alloc((size_t)8192 * 512 * 2);
  short* attnb = (short*)alloc((size_t)8192 * 512 * 2);
  float* x2    = (float*)alloc((size_t)8192 * 512 * 4);
  short* ff1 = hbuf;
  short* h2  = attnb;

  dim3 blk(256);
  conv_kernel<<<(8 * 2048 * 64 + 255) / 256, blk, 0, stream>>>(rel, relb, 8 * 2048 * 64);
  tconv_kernel<<<(512 * 512 + 255) / 256, blk, 0, stream>>>(wq, wqkvT, 512, 512, 1.f);
  tconv_kernel<<<(512 * 512 + 255) / 256, blk, 0, stream>>>(wk, wqkvT + 512 * 512, 512, 512, 0.125f);
  tconv_kernel<<<(512 * 512 + 255) / 256, blk, 0, stream>>>(wv, wqkvT + 1024 * 512, 512, 512, 1.f);
  tconv_kernel<<<(512 * 512 + 255) / 256, blk, 0, stream>>>(w0, w0T, 512, 512, 1.f);
  tconv_kernel<<<(512 * 2048 + 255) / 256, blk, 0, stream>>>(fw1, fw1T, 512, 2048, 1.f);
  tconv_kernel<<<(512 * 2048 + 255) / 256, blk, 0, stream>>>(fw2, fw2T, 2048, 512, 1.f);

  ln_kernel<<<2048, blk, 0, stream>>>(x, ln1g, ln1b, hbuf);
  gemm_kernel<512, 0><<<dim3(12, 64), blk, 0, stream>>>(hbuf, wqkvT, nullptr, nullptr,
                                                        Qb, Kbf, VTb, nullptr);
  attn_kernel<<<512, blk, 0, stream>>>(Qb, Kbf, VTb, relb, attnb);
  gemm_kernel<512, 1><<<dim3(4, 64), blk, 0, stream>>>(attnb, w0T, b0, x,
                                                       nullptr, nullptr, nullptr, x2);
  ln_kernel<<<2048, blk, 0, stream>>>(x2, ln2g, ln2b, h2);
  gemm_kernel<512, 2><<<dim3(16, 64), blk, 0, stream>>>(h2, fw1T, fb1, nullptr,
                                                        ff1, nullptr, nullptr, nullptr);
  gemm_kernel<2048, 1><<<dim3(4, 64), blk, 0, stream>>>(ff1, fw2T, fb2, x2,
                                                        nullptr, nullptr, nullptr, outp);
}